// Round 1
// 561.789 us; speedup vs baseline: 1.2455x; 1.2455x over previous
//
#include <hip/hip_runtime.h>
#include <math.h>

#define N_NODES 100000
#define N_EDGES 1600000
#define HID 48
#define ALPHA 0.1f

typedef unsigned short u16;
typedef unsigned int u32;

__device__ __forceinline__ float bf_lo(u32 u) { return __uint_as_float(u << 16); }
__device__ __forceinline__ float bf_hi(u32 u) { return __uint_as_float(u & 0xffff0000u); }
__device__ __forceinline__ float bf2f(u16 u) {
    return __uint_as_float(((u32)u) << 16);
}
__device__ __forceinline__ u16 f2bf(float f) {
    u32 b = __float_as_uint(f);
    b += 0x7fff + ((b >> 16) & 1);   // round-to-nearest-even
    return (u16)(b >> 16);
}

// ---------------- lin0: h0 = relu(x @ W0 + b0); writes f32 x0 AND bf16 h0 ----------------
__global__ __launch_bounds__(256) void lin0_k(const float* __restrict__ x, const float* __restrict__ W0,
                                              const float* __restrict__ b0, float* __restrict__ x0f,
                                              u16* __restrict__ h0) {
    int t = blockIdx.x * 256 + threadIdx.x;
    if (t >= N_NODES * HID) return;
    int node = t / HID, f = t % HID;
    float v = b0[f]
            + x[node * 3 + 0] * W0[0 * HID + f]
            + x[node * 3 + 1] * W0[1 * HID + f]
            + x[node * 3 + 2] * W0[2 * HID + f];
    v = v > 0.f ? v : 0.f;
    x0f[t] = v;
    h0[t] = f2bf(v);
}

// ---------------- CSR build ----------------
// count + rank capture: the atomic was already paid here; the return value is free.
__global__ __launch_bounds__(256) void count_k(const int* __restrict__ dst, int* __restrict__ deg,
                                               int* __restrict__ rank) {
    int e = blockIdx.x * 256 + threadIdx.x;
    if (e < N_EDGES) rank[e] = atomicAdd(&deg[dst[e]], 1);
}

__global__ __launch_bounds__(256) void scan1_k(const int* __restrict__ deg, int* __restrict__ rowptr,
                                               int* __restrict__ partial) {
    __shared__ int sums[256];
    int tid = threadIdx.x;
    int base = blockIdx.x * 2048 + tid * 8;
    int v[8]; int s = 0;
#pragma unroll
    for (int j = 0; j < 8; j++) { int idx = base + j; v[j] = (idx < N_NODES) ? deg[idx] : 0; s += v[j]; }
    sums[tid] = s; __syncthreads();
    for (int off = 1; off < 256; off <<= 1) {
        int t = (tid >= off) ? sums[tid - off] : 0;
        __syncthreads();
        sums[tid] += t;
        __syncthreads();
    }
    if (tid == 255) partial[blockIdx.x] = sums[255];
    int run = (tid > 0) ? sums[tid - 1] : 0;
#pragma unroll
    for (int j = 0; j < 8; j++) { int idx = base + j; if (idx < N_NODES) rowptr[idx] = run; run += v[j]; }
}

__global__ void scan2_k(int* __restrict__ partial, int* __restrict__ rowptr, int nblk) {
    if (threadIdx.x == 0 && blockIdx.x == 0) {
        int acc = 0;
        for (int i = 0; i < nblk; i++) { int t = partial[i]; partial[i] = acc; acc += t; }
        rowptr[N_NODES] = acc;
    }
}

__global__ __launch_bounds__(256) void scan3_k(int* __restrict__ rowptr, const int* __restrict__ partial) {
    int tid = threadIdx.x;
    int base = blockIdx.x * 2048 + tid * 8;
    int add = partial[blockIdx.x];
#pragma unroll
    for (int j = 0; j < 8; j++) {
        int idx = base + j;
        if (idx < N_NODES) rowptr[idx] += add;
    }
}

// atomic-free scatter: position = rowptr[dst] + rank. Critical path is now just
// dst load -> rowptr gather (L2-hot, 400KB) -> store; no atomic round-trip.
__global__ __launch_bounds__(256) void bucket_k(const int* __restrict__ src, const int* __restrict__ dst,
                                                const int* __restrict__ rank, const int* __restrict__ rowptr,
                                                int* __restrict__ ssrc) {
    int e = blockIdx.x * 256 + threadIdx.x;
    if (e < N_EDGES) {
        int d = dst[e];
        ssrc[rowptr[d] + rank[e]] = src[e];
    }
}

// ---------------- fused layer ----------------
// one wave per node. Gather phase: lane = (chunk 0..11, slot 0..3); each lane loads
// uint2 (4 bf16 features) of edge (e+slot) -> one VMEM instruction covers 4 edges
// (384B) instead of 1 edge (96B). Slot partials rejoined with shfl_xor(1),(2).
__global__ __launch_bounds__(256) void layer_k(const u16* __restrict__ h_in, const float* __restrict__ x0,
                                               const int* __restrict__ rowptr, const int* __restrict__ ssrc,
                                               const float* __restrict__ W, float beta,
                                               u16* __restrict__ h_out) {
    __shared__ float tbuf[4][48];
    int tid = threadIdx.x, wave = tid >> 6, lane = tid & 63;
    int node = blockIdx.x * 4 + wave;
    int chunk = lane >> 2;          // 0..15 (12 active)
    int slot  = lane & 3;           // 0..3  (edge within group)
    bool act = chunk < 12;
    int cc = act ? chunk : 0;       // clamp address for idle lanes (avoid OOB on last row)
    if (node < N_NODES) {
        int e0 = rowptr[node], e1 = rowptr[node + 1];
        float a0 = 0.f, a1 = 0.f, a2 = 0.f, a3 = 0.f;
        int e = e0;
        // main loop: 8 edges per iter, 2 independent 4-edge gathers in flight
        for (; e + 8 <= e1; e += 8) {
            int sA = ssrc[e + slot];
            int sB = ssrc[e + 4 + slot];
            uint2 wA = *(const uint2*)(h_in + sA * 48 + cc * 4);
            uint2 wB = *(const uint2*)(h_in + sB * 48 + cc * 4);
            a0 += bf_lo(wA.x) + bf_lo(wB.x);
            a1 += bf_hi(wA.x) + bf_hi(wB.x);
            a2 += bf_lo(wA.y) + bf_lo(wB.y);
            a3 += bf_hi(wA.y) + bf_hi(wB.y);
        }
        // predicated 4-edge tail
        for (; e < e1; e += 4) {
            int idx = e + slot;
            int s = ssrc[idx < e1 ? idx : e];   // e < e1 here, so ssrc[e] is a safe address
            uint2 w = *(const uint2*)(h_in + s * 48 + cc * 4);
            if (idx < e1) {
                a0 += bf_lo(w.x); a1 += bf_hi(w.x);
                a2 += bf_lo(w.y); a3 += bf_hi(w.y);
            }
        }
        // rejoin the 4 slot partials (lane bits 0-1)
        a0 += __shfl_xor(a0, 1); a0 += __shfl_xor(a0, 2);
        a1 += __shfl_xor(a1, 1); a1 += __shfl_xor(a1, 2);
        a2 += __shfl_xor(a2, 1); a2 += __shfl_xor(a2, 2);
        a3 += __shfl_xor(a3, 1); a3 += __shfl_xor(a3, 2);
        if (act && slot == 0) {
            const float4 xv = *(const float4*)(x0 + (size_t)node * 48 + chunk * 4);
            float4 t;
            t.x = (1.f - ALPHA) * a0 + ALPHA * xv.x;
            t.y = (1.f - ALPHA) * a1 + ALPHA * xv.y;
            t.z = (1.f - ALPHA) * a2 + ALPHA * xv.z;
            t.w = (1.f - ALPHA) * a3 + ALPHA * xv.w;
            ((float4*)tbuf[wave])[chunk] = t;
        }
    }
    __syncthreads();
    if (node < N_NODES && lane < 48) {
        const float4* t4 = (const float4*)tbuf[wave];
        float s = 0.f;
#pragma unroll
        for (int k4 = 0; k4 < 12; k4++) {
            float4 tv = t4[k4];
            s += tv.x * W[(4 * k4 + 0) * 48 + lane] + tv.y * W[(4 * k4 + 1) * 48 + lane]
               + tv.z * W[(4 * k4 + 2) * 48 + lane] + tv.w * W[(4 * k4 + 3) * 48 + lane];
        }
        float t = tbuf[wave][lane];
        float o = (1.f - beta) * t + beta * s;
        h_out[node * 48 + lane] = f2bf(o > 0.f ? o : 0.f);
    }
}

// ---------------- final: out = log_softmax(h @ W1 + b1) ----------------
__global__ __launch_bounds__(256) void final_k(const u16* __restrict__ h, const float* __restrict__ W1,
                                               const float* __restrict__ b1, float* __restrict__ out) {
    __shared__ float tbuf[4][48];
    int tid = threadIdx.x, wave = tid >> 6, lane = tid & 63;
    int node = blockIdx.x * 4 + wave;
    int f = lane < 48 ? lane : 0;
    if (node < N_NODES && lane < 48) tbuf[wave][lane] = bf2f(h[node * 48 + lane]);
    __syncthreads();
    float v = -INFINITY;
    if (node < N_NODES) {
        const float4* t4 = (const float4*)tbuf[wave];
        float s = b1[f];
#pragma unroll
        for (int k4 = 0; k4 < 12; k4++) {
            float4 tv = t4[k4];
            s += tv.x * W1[(4 * k4 + 0) * 48 + f] + tv.y * W1[(4 * k4 + 1) * 48 + f]
               + tv.z * W1[(4 * k4 + 2) * 48 + f] + tv.w * W1[(4 * k4 + 3) * 48 + f];
        }
        if (lane < 48) v = s;
    }
    float m = v;
    for (int off = 32; off >= 1; off >>= 1) m = fmaxf(m, __shfl_xor(m, off));
    float ex = (node < N_NODES && lane < 48) ? expf(v - m) : 0.f;
    float sum = ex;
    for (int off = 32; off >= 1; off >>= 1) sum += __shfl_xor(sum, off);
    if (node < N_NODES && lane < 48) {
        out[node * 48 + lane] = v - m - logf(sum);
    }
}

extern "C" void kernel_launch(void* const* d_in, const int* in_sizes, int n_in,
                              void* d_out, int out_size, void* d_ws, size_t ws_size,
                              hipStream_t stream) {
    const float* x     = (const float*)d_in[0];
    const int*   ei    = (const int*)d_in[1];
    const float* W0    = (const float*)d_in[2];
    const float* b0    = (const float*)d_in[3];
    const float* convW = (const float*)d_in[4];
    const float* W1    = (const float*)d_in[5];
    const float* b1    = (const float*)d_in[6];
    float* out = (float*)d_out;
    const int* src = ei;            // edge_index[0]
    const int* dst = ei + N_EDGES;  // edge_index[1]

    char* ws = (char*)d_ws;
    size_t off = 0;
    float* x0 = (float*)(ws + off); off += (size_t)N_NODES * 48 * 4;   // 19.2 MB f32 residual
    u16* hA   = (u16*)(ws + off);   off += (size_t)N_NODES * 48 * 2;   // 9.6 MB bf16
    u16* hB   = (u16*)(ws + off);   off += (size_t)N_NODES * 48 * 2;   // 9.6 MB bf16
    int* rank = (int*)hB;           // alias: rank (6.4 MB) is dead before hB is first written
    int* ssrc = (int*)(ws + off);   off += (size_t)N_EDGES * 4;        // 6.4 MB
    int* rowptr = (int*)(ws + off); off += (size_t)(N_NODES + 1) * 4;
    off = (off + 255) & ~(size_t)255;
    int* deg = (int*)(ws + off);    off += (size_t)N_NODES * 4;
    off = (off + 255) & ~(size_t)255;
    int* partial = (int*)(ws + off); off += 64 * 4;

    hipMemsetAsync(deg, 0, (size_t)N_NODES * 4, stream);

    lin0_k<<<18750, 256, 0, stream>>>(x, W0, b0, x0, hA);
    count_k<<<6250, 256, 0, stream>>>(dst, deg, rank);
    scan1_k<<<49, 256, 0, stream>>>(deg, rowptr, partial);
    scan2_k<<<1, 64, 0, stream>>>(partial, rowptr, 49);
    scan3_k<<<49, 256, 0, stream>>>(rowptr, partial);
    bucket_k<<<6250, 256, 0, stream>>>(src, dst, rank, rowptr, ssrc);

    const float betas[4] = { logf(1.5f), logf(1.25f), logf(7.f / 6.f), logf(1.125f) };

    layer_k<<<25000, 256, 0, stream>>>(hA, x0, rowptr, ssrc, convW + 0 * 2304, betas[0], hB);
    layer_k<<<25000, 256, 0, stream>>>(hB, x0, rowptr, ssrc, convW + 1 * 2304, betas[1], hA);
    layer_k<<<25000, 256, 0, stream>>>(hA, x0, rowptr, ssrc, convW + 2 * 2304, betas[2], hB);
    layer_k<<<25000, 256, 0, stream>>>(hB, x0, rowptr, ssrc, convW + 3 * 2304, betas[3], hA);
    final_k<<<25000, 256, 0, stream>>>(hA, W1, b1, out);
}

// Round 2
// 518.734 us; speedup vs baseline: 1.3488x; 1.0830x over previous
//
#include <hip/hip_runtime.h>
#include <math.h>

#define N_NODES 100000
#define N_EDGES 1600000
#define HID 48
#define ALPHA 0.1f

typedef unsigned short u16;
typedef unsigned int u32;

__device__ __forceinline__ float bf_lo(u32 u) { return __uint_as_float(u << 16); }
__device__ __forceinline__ float bf_hi(u32 u) { return __uint_as_float(u & 0xffff0000u); }
__device__ __forceinline__ float bf2f(u16 u) {
    return __uint_as_float(((u32)u) << 16);
}
__device__ __forceinline__ u16 f2bf(float f) {
    u32 b = __float_as_uint(f);
    b += 0x7fff + ((b >> 16) & 1);   // round-to-nearest-even
    return (u16)(b >> 16);
}

// ---------------- lin0: h0 = relu(x @ W0 + b0); writes f32 x0 AND bf16 h0 ----------------
__global__ __launch_bounds__(256) void lin0_k(const float* __restrict__ x, const float* __restrict__ W0,
                                              const float* __restrict__ b0, float* __restrict__ x0f,
                                              u16* __restrict__ h0) {
    int t = blockIdx.x * 256 + threadIdx.x;
    if (t >= N_NODES * HID) return;
    int node = t / HID, f = t % HID;
    float v = b0[f]
            + x[node * 3 + 0] * W0[0 * HID + f]
            + x[node * 3 + 1] * W0[1 * HID + f]
            + x[node * 3 + 2] * W0[2 * HID + f];
    v = v > 0.f ? v : 0.f;
    x0f[t] = v;
    h0[t] = f2bf(v);
}

// ---------------- CSR build ----------------
__global__ __launch_bounds__(256) void count_k(const int* __restrict__ dst, int* __restrict__ deg,
                                               int* __restrict__ rank) {
    int e = blockIdx.x * 256 + threadIdx.x;
    if (e < N_EDGES) rank[e] = atomicAdd(&deg[dst[e]], 1);
}

__global__ __launch_bounds__(256) void scan1_k(const int* __restrict__ deg, int* __restrict__ rowptr,
                                               int* __restrict__ partial) {
    __shared__ int sums[256];
    int tid = threadIdx.x;
    int base = blockIdx.x * 2048 + tid * 8;
    int v[8]; int s = 0;
#pragma unroll
    for (int j = 0; j < 8; j++) { int idx = base + j; v[j] = (idx < N_NODES) ? deg[idx] : 0; s += v[j]; }
    sums[tid] = s; __syncthreads();
    for (int off = 1; off < 256; off <<= 1) {
        int t = (tid >= off) ? sums[tid - off] : 0;
        __syncthreads();
        sums[tid] += t;
        __syncthreads();
    }
    if (tid == 255) partial[blockIdx.x] = sums[255];
    int run = (tid > 0) ? sums[tid - 1] : 0;
#pragma unroll
    for (int j = 0; j < 8; j++) { int idx = base + j; if (idx < N_NODES) rowptr[idx] = run; run += v[j]; }
}

// wave-parallel exclusive scan over <=64 block partials (replaces serial loop)
__global__ void scan2_k(int* __restrict__ partial, int* __restrict__ rowptr, int nblk) {
    int lane = threadIdx.x & 63;
    int v = (lane < nblk) ? partial[lane] : 0;
    for (int off = 1; off < 64; off <<= 1) {
        int t = __shfl_up(v, off);
        if (lane >= off) v += t;
    }
    int excl = __shfl_up(v, 1);
    if (lane == 0) excl = 0;
    if (lane < nblk) partial[lane] = excl;
    if (lane == 63) rowptr[N_NODES] = v;
}

__global__ __launch_bounds__(256) void scan3_k(int* __restrict__ rowptr, const int* __restrict__ partial) {
    int tid = threadIdx.x;
    int base = blockIdx.x * 2048 + tid * 8;
    int add = partial[blockIdx.x];
#pragma unroll
    for (int j = 0; j < 8; j++) {
        int idx = base + j;
        if (idx < N_NODES) rowptr[idx] += add;
    }
}

// atomic-free scatter: position = rowptr[dst] + rank
__global__ __launch_bounds__(256) void bucket_k(const int* __restrict__ src, const int* __restrict__ dst,
                                                const int* __restrict__ rank, const int* __restrict__ rowptr,
                                                int* __restrict__ ssrc) {
    int e = blockIdx.x * 256 + threadIdx.x;
    if (e < N_EDGES) {
        int d = dst[e];
        ssrc[rowptr[d] + rank[e]] = src[e];
    }
}

// ---------------- fused layer ----------------
// one wave per node. lane = (slot<<3)|chunk: chunk 0..5 (feature octet), slot 0..7 (edge).
// Each lane gathers uint4 = 8 bf16 features -> one VMEM instruction covers 8 edges (768B).
// 16-edge main iter = 2 independent uint4 gathers in flight; avg-degree-16 node needs ONE iter.
// W is staged in LDS so the epilogue never touches the gather-thrashed L1.
__global__ __launch_bounds__(256) void layer_k(const u16* __restrict__ h_in, const float* __restrict__ x0,
                                               const int* __restrict__ rowptr, const int* __restrict__ ssrc,
                                               const float* __restrict__ W, float beta,
                                               u16* __restrict__ h_out) {
    __shared__ float sW[2304];
    __shared__ float tbuf[4][48];
    int tid = threadIdx.x, wave = tid >> 6, lane = tid & 63;
#pragma unroll
    for (int i = 0; i < 9; i++) sW[i * 256 + tid] = W[i * 256 + tid];
    int node = blockIdx.x * 4 + wave;
    int chunk = lane & 7;           // 0..7 (6 active): feature octet
    int slot  = lane >> 3;          // 0..7: edge within group
    bool act = chunk < 6;
    int cc = act ? chunk : 0;       // clamp idle lanes in-bounds
    float a0 = 0.f, a1 = 0.f, a2 = 0.f, a3 = 0.f, a4 = 0.f, a5 = 0.f, a6 = 0.f, a7 = 0.f;
    if (node < N_NODES) {
        int e0 = rowptr[node], e1 = rowptr[node + 1];
        int e = e0;
        for (; e + 16 <= e1; e += 16) {
            int sA = ssrc[e + slot];
            int sB = ssrc[e + 8 + slot];
            const uint4 wA = *(const uint4*)(h_in + (size_t)sA * 48 + cc * 8);
            const uint4 wB = *(const uint4*)(h_in + (size_t)sB * 48 + cc * 8);
            a0 += bf_lo(wA.x) + bf_lo(wB.x);
            a1 += bf_hi(wA.x) + bf_hi(wB.x);
            a2 += bf_lo(wA.y) + bf_lo(wB.y);
            a3 += bf_hi(wA.y) + bf_hi(wB.y);
            a4 += bf_lo(wA.z) + bf_lo(wB.z);
            a5 += bf_hi(wA.z) + bf_hi(wB.z);
            a6 += bf_lo(wA.w) + bf_lo(wB.w);
            a7 += bf_hi(wA.w) + bf_hi(wB.w);
        }
        // predicated 8-edge tail
        for (; e < e1; e += 8) {
            int idx = e + slot;
            int s = ssrc[idx < e1 ? idx : e];   // e < e1 here, ssrc[e] is a safe address
            const uint4 w = *(const uint4*)(h_in + (size_t)s * 48 + cc * 8);
            if (idx < e1) {
                a0 += bf_lo(w.x); a1 += bf_hi(w.x);
                a2 += bf_lo(w.y); a3 += bf_hi(w.y);
                a4 += bf_lo(w.z); a5 += bf_hi(w.z);
                a6 += bf_lo(w.w); a7 += bf_hi(w.w);
            }
        }
        // rejoin the 8 slot partials (lane bits 3,4,5)
#pragma unroll
        for (int off = 8; off <= 32; off <<= 1) {
            a0 += __shfl_xor(a0, off); a1 += __shfl_xor(a1, off);
            a2 += __shfl_xor(a2, off); a3 += __shfl_xor(a3, off);
            a4 += __shfl_xor(a4, off); a5 += __shfl_xor(a5, off);
            a6 += __shfl_xor(a6, off); a7 += __shfl_xor(a7, off);
        }
        if (act && slot == 0) {
            const float4 xv0 = *(const float4*)(x0 + (size_t)node * 48 + chunk * 8);
            const float4 xv1 = *(const float4*)(x0 + (size_t)node * 48 + chunk * 8 + 4);
            float4 t0, t1;
            t0.x = (1.f - ALPHA) * a0 + ALPHA * xv0.x;
            t0.y = (1.f - ALPHA) * a1 + ALPHA * xv0.y;
            t0.z = (1.f - ALPHA) * a2 + ALPHA * xv0.z;
            t0.w = (1.f - ALPHA) * a3 + ALPHA * xv0.w;
            t1.x = (1.f - ALPHA) * a4 + ALPHA * xv1.x;
            t1.y = (1.f - ALPHA) * a5 + ALPHA * xv1.y;
            t1.z = (1.f - ALPHA) * a6 + ALPHA * xv1.z;
            t1.w = (1.f - ALPHA) * a7 + ALPHA * xv1.w;
            ((float4*)tbuf[wave])[chunk * 2 + 0] = t0;
            ((float4*)tbuf[wave])[chunk * 2 + 1] = t1;
        }
    }
    __syncthreads();
    if (node < N_NODES && lane < 48) {
        const float4* t4 = (const float4*)tbuf[wave];
        float s = 0.f;
#pragma unroll
        for (int k4 = 0; k4 < 12; k4++) {
            float4 tv = t4[k4];
            s += tv.x * sW[(4 * k4 + 0) * 48 + lane] + tv.y * sW[(4 * k4 + 1) * 48 + lane]
               + tv.z * sW[(4 * k4 + 2) * 48 + lane] + tv.w * sW[(4 * k4 + 3) * 48 + lane];
        }
        float t = tbuf[wave][lane];
        float o = (1.f - beta) * t + beta * s;
        h_out[node * 48 + lane] = f2bf(o > 0.f ? o : 0.f);
    }
}

// ---------------- final: out = log_softmax(h @ W1 + b1) ----------------
__global__ __launch_bounds__(256) void final_k(const u16* __restrict__ h, const float* __restrict__ W1,
                                               const float* __restrict__ b1, float* __restrict__ out) {
    __shared__ float sW[2304];
    __shared__ float sb[48];
    __shared__ float tbuf[4][48];
    int tid = threadIdx.x, wave = tid >> 6, lane = tid & 63;
#pragma unroll
    for (int i = 0; i < 9; i++) sW[i * 256 + tid] = W1[i * 256 + tid];
    if (tid < 48) sb[tid] = b1[tid];
    int node = blockIdx.x * 4 + wave;
    int f = lane < 48 ? lane : 0;
    if (node < N_NODES && lane < 48) tbuf[wave][lane] = bf2f(h[node * 48 + lane]);
    __syncthreads();
    float v = -INFINITY;
    if (node < N_NODES) {
        const float4* t4 = (const float4*)tbuf[wave];
        float s = sb[f];
#pragma unroll
        for (int k4 = 0; k4 < 12; k4++) {
            float4 tv = t4[k4];
            s += tv.x * sW[(4 * k4 + 0) * 48 + f] + tv.y * sW[(4 * k4 + 1) * 48 + f]
               + tv.z * sW[(4 * k4 + 2) * 48 + f] + tv.w * sW[(4 * k4 + 3) * 48 + f];
        }
        if (lane < 48) v = s;
    }
    float m = v;
    for (int off = 32; off >= 1; off >>= 1) m = fmaxf(m, __shfl_xor(m, off));
    float ex = (node < N_NODES && lane < 48) ? expf(v - m) : 0.f;
    float sum = ex;
    for (int off = 32; off >= 1; off >>= 1) sum += __shfl_xor(sum, off);
    if (node < N_NODES && lane < 48) {
        out[node * 48 + lane] = v - m - logf(sum);
    }
}

extern "C" void kernel_launch(void* const* d_in, const int* in_sizes, int n_in,
                              void* d_out, int out_size, void* d_ws, size_t ws_size,
                              hipStream_t stream) {
    const float* x     = (const float*)d_in[0];
    const int*   ei    = (const int*)d_in[1];
    const float* W0    = (const float*)d_in[2];
    const float* b0    = (const float*)d_in[3];
    const float* convW = (const float*)d_in[4];
    const float* W1    = (const float*)d_in[5];
    const float* b1    = (const float*)d_in[6];
    float* out = (float*)d_out;
    const int* src = ei;            // edge_index[0]
    const int* dst = ei + N_EDGES;  // edge_index[1]

    char* ws = (char*)d_ws;
    size_t off = 0;
    float* x0 = (float*)(ws + off); off += (size_t)N_NODES * 48 * 4;   // 19.2 MB f32 residual
    u16* hA   = (u16*)(ws + off);   off += (size_t)N_NODES * 48 * 2;   // 9.6 MB bf16
    u16* hB   = (u16*)(ws + off);   off += (size_t)N_NODES * 48 * 2;   // 9.6 MB bf16
    int* rank = (int*)hB;           // alias: rank (6.4 MB) is dead before hB is first written
    int* ssrc = (int*)(ws + off);   off += (size_t)N_EDGES * 4;        // 6.4 MB
    int* rowptr = (int*)(ws + off); off += (size_t)(N_NODES + 1) * 4;
    off = (off + 255) & ~(size_t)255;
    int* cursorUnused = (int*)(ws + off); off += (size_t)N_NODES * 4;
    off = (off + 255) & ~(size_t)255;
    int* deg = (int*)(ws + off);    off += (size_t)N_NODES * 4;
    off = (off + 255) & ~(size_t)255;
    int* partial = (int*)(ws + off); off += 64 * 4;
    (void)cursorUnused;

    hipMemsetAsync(deg, 0, (size_t)N_NODES * 4, stream);

    lin0_k<<<18750, 256, 0, stream>>>(x, W0, b0, x0, hA);
    count_k<<<6250, 256, 0, stream>>>(dst, deg, rank);
    scan1_k<<<49, 256, 0, stream>>>(deg, rowptr, partial);
    scan2_k<<<1, 64, 0, stream>>>(partial, rowptr, 49);
    scan3_k<<<49, 256, 0, stream>>>(rowptr, partial);
    bucket_k<<<6250, 256, 0, stream>>>(src, dst, rank, rowptr, ssrc);

    const float betas[4] = { logf(1.5f), logf(1.25f), logf(7.f / 6.f), logf(1.125f) };

    layer_k<<<25000, 256, 0, stream>>>(hA, x0, rowptr, ssrc, convW + 0 * 2304, betas[0], hB);
    layer_k<<<25000, 256, 0, stream>>>(hB, x0, rowptr, ssrc, convW + 1 * 2304, betas[1], hA);
    layer_k<<<25000, 256, 0, stream>>>(hA, x0, rowptr, ssrc, convW + 2 * 2304, betas[2], hB);
    layer_k<<<25000, 256, 0, stream>>>(hB, x0, rowptr, ssrc, convW + 3 * 2304, betas[3], hA);
    final_k<<<25000, 256, 0, stream>>>(hA, W1, b1, out);
}